// Round 4
// baseline (276.953 us; speedup 1.0000x reference)
//
#include <hip/hip_runtime.h>
#include <stdint.h>

/* AdditiveAttention (B=4, Q=256, K=1024, D=512, H=256)
 * out[b,i,v] = sum_j softmax_j(sum_h tanh(q[b,i,h]+k[b,j,h])*wv[h]) * values[b,j,v],
 * masked to j < valid_lens[b].  OUTPUT IS FLOAT32 (R20 finding).
 *
 * R24: (a) revert attn to QROWS=4 (R3's QROWS=2 doubled kp/values L2 streams,
 * net loss). (b) attn: drop softmax max-pass — after the global sumW shift
 * (row-constant, cancels) scores are bounded ~|28|, exp() is fp32-safe; P1
 * emits E=exp directly + wave sum-reduce; 1/S folded into PV partials. One
 * barrier and the whole P2 LDS round-trip eliminated. (c) attn: vl-aware
 * skip — waves with k >= vl skip P1; P3 caps k-loops at vl; final reduce
 * sums ceil(vl/256) quarters (E==0 exactly for masked k). (d) proj h-block=4:
 * thread owns 4h x 2rows -> per d4: 2 LDS b128 + 4 W float4 + 32 FMA
 * (was 8 LDS per 32 FMA: LDS-issue-bound). WT repacked 64B/lane. */

#define NB 4
#define NQ 256
#define NK 1024
#define ND 512
#define NH 256
#define QROWS 4

#define C2L2E 2.8853900817779268f   /* 2*log2(e) */
#define L2E   1.4426950408889634f   /* log2(e)   */

/* 8-class valid_lens decode: {i32,i64,f32,f64,i16,f16,bf16,fallback}. */
__device__ void ff_vldec(const int* p, int* v) {
  bool ok = true;
  for (int i = 0; i < 4; ++i) { int x = p[i]; if (x < 1 || x > NK) ok = false; }
  if (ok) { for (int i = 0; i < 4; ++i) v[i] = p[i]; return; }
  ok = true;
  for (int i = 0; i < 4; ++i) {
    if (p[2 * i + 1] != 0) ok = false;
    int x = p[2 * i]; if (x < 1 || x > NK) ok = false;
  }
  if (ok) { for (int i = 0; i < 4; ++i) v[i] = p[2 * i]; return; }
  ok = true;
  for (int i = 0; i < 4; ++i) {
    union { int i; float f; } u; u.i = p[i];
    if (!(u.f >= 1.0f && u.f <= 1024.0f && u.f == floorf(u.f))) ok = false;
  }
  if (ok) {
    for (int i = 0; i < 4; ++i) { union { int i; float f; } u; u.i = p[i]; v[i] = (int)u.f; }
    return;
  }
  ok = true;
  for (int i = 0; i < 4; ++i) {
    union { long long l; double d; } u;
    u.l = ((long long)p[2 * i + 1] << 32) | (unsigned int)p[2 * i];
    if (!(u.d >= 1.0 && u.d <= 1024.0 && u.d == floor(u.d))) ok = false;
  }
  if (ok) {
    for (int i = 0; i < 4; ++i) {
      union { long long l; double d; } u;
      u.l = ((long long)p[2 * i + 1] << 32) | (unsigned int)p[2 * i];
      v[i] = (int)u.d;
    }
    return;
  }
  const uint16_t* hh = (const uint16_t*)p;
  const short*    s  = (const short*)p;
  ok = true;
  for (int i = 0; i < 4; ++i) { int x = s[i]; if (x < 1 || x > NK) ok = false; }
  if (ok) { for (int i = 0; i < 4; ++i) v[i] = s[i]; return; }
  ok = true;
  for (int i = 0; i < 4; ++i) {
    union { uint16_t u; _Float16 h; } u; u.u = hh[i];
    float f = (float)u.h;
    if (!(f >= 1.0f && f <= 1024.0f && f == floorf(f))) ok = false;
  }
  if (ok) {
    for (int i = 0; i < 4; ++i) {
      union { uint16_t u; _Float16 h; } u; u.u = hh[i];
      v[i] = (int)(float)u.h;
    }
    return;
  }
  ok = true;
  for (int i = 0; i < 4; ++i) {
    union { uint32_t u; float f; } u; u.u = ((uint32_t)hh[i]) << 16;
    if (!(u.f >= 1.0f && u.f <= 1028.0f)) ok = false;
  }
  if (ok) {
    for (int i = 0; i < 4; ++i) {
      union { uint32_t u; float f; } u; u.u = ((uint32_t)hh[i]) << 16;
      int x = (int)(u.f + 0.5f); if (x > NK) x = NK; v[i] = x;
    }
    return;
  }
  for (int i = 0; i < 4; ++i) v[i] = NK;  /* fail-safe: unmasked */
}

/* Repack W[h][d] -> WT2: group (d4, hg=h>>2): 16 floats = C2L2E*W[4hg+j][4d4..]
 * at WT2[(d4*64+hg)*16 + j*4].  Proj lane hg then reads 64B contiguous. */
__global__ __launch_bounds__(256) void ff_wt(
    const float* __restrict__ Wq, const float* __restrict__ Wk,
    float* __restrict__ WTq, float* __restrict__ WTk)
{
  const int idx = blockIdx.x * 256 + threadIdx.x;   /* 0..32767 */
  const int d4 = idx & 127, h = idx >> 7;
  const float* src = blockIdx.y ? Wk : Wq;
  float*       dst = blockIdx.y ? WTk : WTq;
  float4 w = *(const float4*)(src + (size_t)h * ND + d4 * 4);
  w.x *= C2L2E; w.y *= C2L2E; w.z *= C2L2E; w.w *= C2L2E;
  *(float4*)(dst + ((size_t)d4 * 64 + (h >> 2)) * 16 + (h & 3) * 4) = w;
}

/* Merged projection: blocks [0,128) -> queries (qp[r][h]), [128,640) -> keys
 * (kp[b][h][k], transposed store). 8 rows/block. Thread: hg=t&63 owns
 * h=4hg..4hg+3; rg=t>>6 owns rows 2rg,2rg+1. Per d4: 2 LDS b128 (x rows,
 * broadcast) + 4 W float4 (64B/lane coalesced) + 32 FMA -> FMA-bound. */
__global__ __launch_bounds__(256) void ff_proj(
    const float* __restrict__ q_in, const float* __restrict__ k_in,
    const float* __restrict__ WTq, const float* __restrict__ WTk,
    float* __restrict__ qp, float* __restrict__ kp)
{
  __shared__ float xs[8 * ND];                   /* 16 KB */
  const int t = threadIdx.x;
  const bool isq = blockIdx.x < (NB * NQ / 8);
  const int g = isq ? blockIdx.x : (blockIdx.x - NB * NQ / 8);
  const float* xin = (isq ? q_in : k_in) + (size_t)g * 8 * ND;
  const float* WT  = isq ? WTq : WTk;

  #pragma unroll
  for (int i = 0; i < 4; ++i)
    ((float4*)xs)[t + 256 * i] = ((const float4*)xin)[t + 256 * i];
  __syncthreads();

  const int hg = t & 63, rg = t >> 6;
  float ac[4][2];
  #pragma unroll
  for (int j = 0; j < 4; ++j) { ac[j][0] = 0.f; ac[j][1] = 0.f; }

  const float* wbase = WT + (size_t)hg * 16;
  #pragma unroll 2
  for (int d4 = 0; d4 < ND / 4; ++d4) {
    const float* wp = wbase + (size_t)d4 * 64 * 16;
    float4 x0 = *(const float4*)&xs[(2 * rg    ) * ND + d4 * 4];
    float4 x1 = *(const float4*)&xs[(2 * rg + 1) * ND + d4 * 4];
    #pragma unroll
    for (int j = 0; j < 4; ++j) {
      float4 w = *(const float4*)(wp + j * 4);
      ac[j][0] += w.x*x0.x + w.y*x0.y + w.z*x0.z + w.w*x0.w;
      ac[j][1] += w.x*x1.x + w.y*x1.y + w.z*x1.z + w.w*x1.w;
    }
  }

  if (isq) {
    float* o = qp + ((size_t)g * 8) * NH;
    *(float4*)(o + (size_t)(2*rg    ) * NH + 4*hg) = make_float4(ac[0][0], ac[1][0], ac[2][0], ac[3][0]);
    *(float4*)(o + (size_t)(2*rg + 1) * NH + 4*hg) = make_float4(ac[0][1], ac[1][1], ac[2][1], ac[3][1]);
  } else {
    const int r0 = g * 8;
    const int bb = r0 >> 10, rk = r0 & (NK - 1);
    float* o = kp + ((size_t)bb * NH + 4*hg) * NK + rk + 2*rg;
    #pragma unroll
    for (int j = 0; j < 4; ++j)
      *(float2*)(o + (size_t)j * NK) = make_float2(ac[j][0], ac[j][1]);
  }
}

/* Fused scores + softmax + PV.  1024 threads, QROWS=4, grid (64,4)=256.
 * P1: thread owns k=t; E = exp(score') stored unnormalized (no max pass:
 * |score'| <~ 28 after sumW shift), masked->0 exactly; wave sum-reduce.
 * P3: split-k PV capped at vl, 1/S folded into partial stores.  F32 out. */
__global__ __launch_bounds__(1024) void ff_attn(
    const float* __restrict__ qp, const float* __restrict__ kp,
    const float* __restrict__ vals, const int* __restrict__ vlraw,
    const float* __restrict__ wvp, float* __restrict__ out)
{
  __shared__ float qs[NH * QROWS];        /* [h][row], pre-scaled      4 KB */
  __shared__ float ws[NH];                /* -2*wv                     1 KB */
  __shared__ float st[NK * QROWS];        /* [k][row] E values        16 KB */
  __shared__ float psum[16 * 4];          /* per-wave row sums       256 B  */
  __shared__ float part[4 * QROWS * ND];  /* split-k partials         32 KB */

  const int t  = threadIdx.x;
  const int q0 = blockIdx.x * QROWS;
  const int b  = blockIdx.y;

  {
    const float* qsrc = qp + ((size_t)b * NQ + q0) * NH;
    const int row = t >> 8, h = t & 255;
    qs[h * QROWS + row] = qsrc[t];        /* qsrc[row*NH+h] == qsrc[t] */
    if (t < NH) ws[t] = -2.0f * wvp[t];
  }
  __syncthreads();

  int vls[4];
  ff_vldec(vlraw, vls);
  const int vl = vls[b];

  /* ---- phase 1: scores -> E, thread owns k = t ---- */
  float a0 = 0.f, a1 = 0.f, a2 = 0.f, a3 = 0.f;
  if ((t & ~63) < vl) {                   /* wave-uniform skip */
    const float* kvp = kp + (size_t)b * NH * NK + t;
    #pragma unroll 8
    for (int h = 0; h < NH; ++h) {
      float  kv = kvp[(size_t)h * NK];
      float4 q4 = *(const float4*)(qs + h * QROWS);
      float  w  = ws[h];
      a0 += w * __builtin_amdgcn_rcpf(1.0f + __builtin_amdgcn_exp2f(q4.x + kv));
      a1 += w * __builtin_amdgcn_rcpf(1.0f + __builtin_amdgcn_exp2f(q4.y + kv));
      a2 += w * __builtin_amdgcn_rcpf(1.0f + __builtin_amdgcn_exp2f(q4.z + kv));
      a3 += w * __builtin_amdgcn_rcpf(1.0f + __builtin_amdgcn_exp2f(q4.w + kv));
    }
  }
  float e0, e1, e2, e3;
  {
    const bool okm = (t < vl);
    e0 = okm ? __builtin_amdgcn_exp2f(a0 * L2E) : 0.f;
    e1 = okm ? __builtin_amdgcn_exp2f(a1 * L2E) : 0.f;
    e2 = okm ? __builtin_amdgcn_exp2f(a2 * L2E) : 0.f;
    e3 = okm ? __builtin_amdgcn_exp2f(a3 * L2E) : 0.f;
    *(float4*)&st[t * 4] = make_float4(e0, e1, e2, e3);
    float s0 = e0, s1 = e1, s2 = e2, s3 = e3;
    for (int o = 32; o; o >>= 1) {
      s0 += __shfl_xor(s0, o); s1 += __shfl_xor(s1, o);
      s2 += __shfl_xor(s2, o); s3 += __shfl_xor(s3, o);
    }
    if ((t & 63) == 0)
      *(float4*)&psum[(t >> 6) * 4] = make_float4(s0, s1, s2, s3);
  }
  __syncthreads();

  /* row sums -> reciprocals (block-uniform) */
  float4 S = make_float4(0.f, 0.f, 0.f, 0.f);
  #pragma unroll
  for (int w = 0; w < 16; ++w) {
    float4 p = *(const float4*)&psum[w * 4];
    S.x += p.x; S.y += p.y; S.z += p.z; S.w += p.w;
  }
  const float r0 = 1.0f / S.x, r1 = 1.0f / S.y, r2 = 1.0f / S.z, r3 = 1.0f / S.w;

  /* ---- phase 3: PV, split-k quarters capped at vl ---- */
  {
    const int kq = t >> 8, c2 = (t & 255) * 2;
    const int k0 = kq * 256;
    if (k0 < vl) {
      const int kend = (k0 + 256 < vl) ? k0 + 256 : vl;
      const float* vb = vals + (size_t)b * NK * ND + c2;
      float ox0=0.f, oy0=0.f, ox1=0.f, oy1=0.f;
      float ox2=0.f, oy2=0.f, ox3=0.f, oy3=0.f;
      #pragma unroll 8
      for (int k = k0; k < kend; ++k) {
        float2 v2 = *(const float2*)(vb + (size_t)k * ND);
        float4 a  = *(const float4*)&st[k * 4];
        ox0 += a.x * v2.x; oy0 += a.x * v2.y;
        ox1 += a.y * v2.x; oy1 += a.y * v2.y;
        ox2 += a.z * v2.x; oy2 += a.z * v2.y;
        ox3 += a.w * v2.x; oy3 += a.w * v2.y;
      }
      float* pp = &part[(size_t)kq * QROWS * ND + c2];
      *(float2*)(pp         ) = make_float2(ox0 * r0, oy0 * r0);
      *(float2*)(pp +     ND) = make_float2(ox1 * r1, oy1 * r1);
      *(float2*)(pp + 2 * ND) = make_float2(ox2 * r2, oy2 * r2);
      *(float2*)(pp + 3 * ND) = make_float2(ox3 * r3, oy3 * r3);
    }
  }
  __syncthreads();
  {
    const int nq = (vl + 255) >> 8;       /* quarters that wrote partials */
    const int r = t >> 8, c2 = (t & 255) * 2;
    const float* pp = &part[(size_t)r * ND + c2];
    float2 s = make_float2(0.f, 0.f);
    for (int kq = 0; kq < nq; ++kq) {
      float2 p = *(const float2*)(pp + (size_t)kq * QROWS * ND);
      s.x += p.x; s.y += p.y;
    }
    *(float2*)(out + ((size_t)b * NQ + q0 + r) * ND + c2) = s;
  }
}

extern "C" void kernel_launch(void* const* d_in, const int* in_sizes, int n_in,
                              void* d_out, int out_size, void* d_ws, size_t ws_size,
                              hipStream_t stream) {
  const float* queries = (const float*)d_in[0];
  const float* keys    = (const float*)d_in[1];
  const float* values  = (const float*)d_in[2];
  const int*   vlens   = (const int*)d_in[3];
  const float* Wq      = (const float*)d_in[4];
  const float* Wk      = (const float*)d_in[5];
  const float* wv      = (const float*)d_in[6];
  float* out = (float*)d_out;               /* F32 OUTPUT */

  float* qp  = (float*)d_ws;                /* [B][Q][H]   1 MB, pre-scaled */
  float* kp  = qp  + (size_t)NB * NQ * NH;  /* [B][H][K]   4 MB, pre-scaled */
  float* wtq = kp  + (size_t)NB * NH * NK;  /* repacked    512 KB */
  float* wtk = wtq + (size_t)(ND / 4) * NH * 4; /*         512 KB */

  ff_wt  <<<dim3(128, 2), 256, 0, stream>>>(Wq, Wk, wtq, wtk);
  ff_proj<<<dim3(NB * NQ / 8 + NB * NK / 8), 256, 0, stream>>>(
      queries, keys, wtq, wtk, qp, kp);
  ff_attn<<<dim3(NQ / QROWS, NB), 1024, 0, stream>>>(qp, kp, values, vlens, wv, out);
}

// Round 5
// 245.219 us; speedup vs baseline: 1.1294x; 1.1294x over previous
//
#include <hip/hip_runtime.h>
#include <stdint.h>

/* AdditiveAttention (B=4, Q=256, K=1024, D=512, H=256)
 * out[b,i,v] = sum_j softmax_j(sum_h tanh(q[b,i,h]+k[b,j,h])*wv[h]) * values[b,j,v],
 * masked to j < valid_lens[b].  OUTPUT IS FLOAT32 (R20 finding).
 *
 * R25: (a) attn reverted EXACTLY to R2's QROWS=4 version (103us tight,
 * VALUBusy 57%) — R4's no-max/vl-skip restructure collapsed VALUBusy to 15%
 * and regressed. (b) proj: 16 rows/block (was 8). Every prior proj made each
 * block stream the full 512KB WT from L2 for only 8 rows of output (320MB L2
 * traffic) and issued 8 LDS b128 per 32 FMA (LDS-issue-bound). At 16 rows:
 * 1 coalesced W float4 + 16 broadcast b128 + 64 FMA per d4 -> FMA-bound,
 * WT traffic halved, 2 blocks/CU (32KB xs) for latency hiding.
 * (c) ff_wt reverted to R2 [d4][NH]x16B layout (R4's repack gave 64-line
 * wave loads). */

#define NB 4
#define NQ 256
#define NK 1024
#define ND 512
#define NH 256
#define QROWS 4
#define PRJ_R 16

#define C2L2E 2.8853900817779268f   /* 2*log2(e) */
#define L2E   1.4426950408889634f   /* log2(e)   */

/* 8-class valid_lens decode: {i32,i64,f32,f64,i16,f16,bf16,fallback}. */
__device__ void ff_vldec(const int* p, int* v) {
  bool ok = true;
  for (int i = 0; i < 4; ++i) { int x = p[i]; if (x < 1 || x > NK) ok = false; }
  if (ok) { for (int i = 0; i < 4; ++i) v[i] = p[i]; return; }
  ok = true;
  for (int i = 0; i < 4; ++i) {
    if (p[2 * i + 1] != 0) ok = false;
    int x = p[2 * i]; if (x < 1 || x > NK) ok = false;
  }
  if (ok) { for (int i = 0; i < 4; ++i) v[i] = p[2 * i]; return; }
  ok = true;
  for (int i = 0; i < 4; ++i) {
    union { int i; float f; } u; u.i = p[i];
    if (!(u.f >= 1.0f && u.f <= 1024.0f && u.f == floorf(u.f))) ok = false;
  }
  if (ok) {
    for (int i = 0; i < 4; ++i) { union { int i; float f; } u; u.i = p[i]; v[i] = (int)u.f; }
    return;
  }
  ok = true;
  for (int i = 0; i < 4; ++i) {
    union { long long l; double d; } u;
    u.l = ((long long)p[2 * i + 1] << 32) | (unsigned int)p[2 * i];
    if (!(u.d >= 1.0 && u.d <= 1024.0 && u.d == floor(u.d))) ok = false;
  }
  if (ok) {
    for (int i = 0; i < 4; ++i) {
      union { long long l; double d; } u;
      u.l = ((long long)p[2 * i + 1] << 32) | (unsigned int)p[2 * i];
      v[i] = (int)u.d;
    }
    return;
  }
  const uint16_t* hh = (const uint16_t*)p;
  const short*    s  = (const short*)p;
  ok = true;
  for (int i = 0; i < 4; ++i) { int x = s[i]; if (x < 1 || x > NK) ok = false; }
  if (ok) { for (int i = 0; i < 4; ++i) v[i] = s[i]; return; }
  ok = true;
  for (int i = 0; i < 4; ++i) {
    union { uint16_t u; _Float16 h; } u; u.u = hh[i];
    float f = (float)u.h;
    if (!(f >= 1.0f && f <= 1024.0f && f == floorf(f))) ok = false;
  }
  if (ok) {
    for (int i = 0; i < 4; ++i) {
      union { uint16_t u; _Float16 h; } u; u.u = hh[i];
      v[i] = (int)(float)u.h;
    }
    return;
  }
  ok = true;
  for (int i = 0; i < 4; ++i) {
    union { uint32_t u; float f; } u; u.u = ((uint32_t)hh[i]) << 16;
    if (!(u.f >= 1.0f && u.f <= 1028.0f)) ok = false;
  }
  if (ok) {
    for (int i = 0; i < 4; ++i) {
      union { uint32_t u; float f; } u; u.u = ((uint32_t)hh[i]) << 16;
      int x = (int)(u.f + 0.5f); if (x > NK) x = NK; v[i] = x;
    }
    return;
  }
  for (int i = 0; i < 4; ++i) v[i] = NK;  /* fail-safe: unmasked */
}

/* Transpose W[h][d] -> WT float4 #(d4*NH+h) = C2L2E * W[h][4d4..4d4+3]. */
__global__ __launch_bounds__(256) void ff_wt(
    const float* __restrict__ Wq, const float* __restrict__ Wk,
    float* __restrict__ WTq, float* __restrict__ WTk)
{
  const int idx = blockIdx.x * 256 + threadIdx.x;   /* 0..32767 */
  const int d4 = idx & 127, h = idx >> 7;
  const float* src = blockIdx.y ? Wk : Wq;
  float*       dst = blockIdx.y ? WTk : WTq;
  float4 w = *(const float4*)(src + (size_t)h * ND + d4 * 4);
  w.x *= C2L2E; w.y *= C2L2E; w.z *= C2L2E; w.w *= C2L2E;
  *(float4*)(dst + ((size_t)d4 * NH + h) * 4) = w;
}

/* Merged projection: blocks [0,64) -> queries (qp[r][h]), [64,320) -> keys
 * (kp[b][h][k], transposed store). Thread owns h=t for PRJ_R=16 rows.
 * Per d4: 1 coalesced W float4 (16B/lane, 1KB/wave) + 16 broadcast LDS b128
 * + 64 FMA -> FMA-bound. 32KB xs -> 2 blocks/CU. */
__global__ __launch_bounds__(256) void ff_proj(
    const float* __restrict__ q_in, const float* __restrict__ k_in,
    const float* __restrict__ WTq, const float* __restrict__ WTk,
    float* __restrict__ qp, float* __restrict__ kp)
{
  __shared__ float xs[PRJ_R * ND];               /* 32 KB */
  const int t = threadIdx.x;
  const bool isq = blockIdx.x < (NB * NQ / PRJ_R);
  const int g = isq ? blockIdx.x : (blockIdx.x - NB * NQ / PRJ_R);
  const float* xin = (isq ? q_in : k_in) + (size_t)g * PRJ_R * ND;
  const float* WT  = isq ? WTq : WTk;

  #pragma unroll
  for (int i = 0; i < PRJ_R * ND / 4 / 256; ++i)   /* 8 float4 each */
    ((float4*)xs)[t + 256 * i] = ((const float4*)xin)[t + 256 * i];
  __syncthreads();

  float acc[PRJ_R];
  #pragma unroll
  for (int r = 0; r < PRJ_R; ++r) acc[r] = 0.f;

  #pragma unroll 2
  for (int d4 = 0; d4 < ND / 4; ++d4) {
    float4 w = *(const float4*)(WT + ((size_t)d4 * NH + t) * 4);
    #pragma unroll
    for (int r = 0; r < PRJ_R; ++r) {
      float4 x = *(const float4*)&xs[r * ND + d4 * 4];
      acc[r] += w.x * x.x + w.y * x.y + w.z * x.z + w.w * x.w;
    }
  }

  if (isq) {
    float* o = qp + (size_t)g * PRJ_R * NH + t;
    #pragma unroll
    for (int r = 0; r < PRJ_R; ++r) o[(size_t)r * NH] = acc[r];
  } else {
    const int r0 = g * PRJ_R;
    const int bb = r0 >> 10, rk = r0 & (NK - 1);
    float* o = kp + ((size_t)bb * NH + t) * NK + rk;
    #pragma unroll
    for (int r = 0; r < PRJ_R; r += 4)
      *(float4*)(o + r) = make_float4(acc[r], acc[r+1], acc[r+2], acc[r+3]);
  }
}

/* Fused scores + masked softmax + PV.  1024 threads, 4 q-rows per block.
 * (R2-exact version: 103us, VALUBusy 57%.)
 * Phase1: thread owns k=t; score' = sum_h (-2*wv_h)/(1+exp2(q'+k'))
 * (sumW cancels in softmax; q',k' pre-scaled by 2*log2e).
 * Phase2: 4 waves/row softmax. Phase3: split-k PV + LDS reduce. F32 out. */
__global__ __launch_bounds__(1024) void ff_attn(
    const float* __restrict__ qp, const float* __restrict__ kp,
    const float* __restrict__ vals, const int* __restrict__ vlraw,
    const float* __restrict__ wvp, float* __restrict__ out)
{
  __shared__ float qs[NH * QROWS];        /* [h][row], pre-scaled      4 KB */
  __shared__ float ws[NH];                /* -2*wv                     1 KB */
  __shared__ float st[NK * QROWS];        /* [k][row] scores->probs   16 KB */
  __shared__ float pm[16], psm[16];
  __shared__ float part[4 * QROWS * ND];  /* split-k partials         32 KB */

  const int t  = threadIdx.x;
  const int q0 = blockIdx.x * QROWS;
  const int b  = blockIdx.y;

  {
    const float* qsrc = qp + ((size_t)b * NQ + q0) * NH;
    const int row = t >> 8, h = t & 255;
    qs[h * QROWS + row] = qsrc[t];        /* qsrc[row*NH+h] == qsrc[t] */
    if (t < NH) ws[t] = -2.0f * wvp[t];
  }
  __syncthreads();

  int vls[4];
  ff_vldec(vlraw, vls);
  const int vl = vls[b];

  /* ---- phase 1: scores, thread owns k = t ---- */
  float a0 = 0.f, a1 = 0.f, a2 = 0.f, a3 = 0.f;
  {
    const float* kvp = kp + (size_t)b * NH * NK + t;
    #pragma unroll 8
    for (int h = 0; h < NH; ++h) {
      float  kv = kvp[(size_t)h * NK];
      float4 q4 = *(const float4*)(qs + h * QROWS);
      float  w  = ws[h];
      a0 += w * __builtin_amdgcn_rcpf(1.0f + __builtin_amdgcn_exp2f(q4.x + kv));
      a1 += w * __builtin_amdgcn_rcpf(1.0f + __builtin_amdgcn_exp2f(q4.y + kv));
      a2 += w * __builtin_amdgcn_rcpf(1.0f + __builtin_amdgcn_exp2f(q4.z + kv));
      a3 += w * __builtin_amdgcn_rcpf(1.0f + __builtin_amdgcn_exp2f(q4.w + kv));
    }
  }
  {
    const bool okm = (t < vl);
    *(float4*)&st[t * 4] = make_float4(okm ? a0 : -1e6f, okm ? a1 : -1e6f,
                                       okm ? a2 : -1e6f, okm ? a3 : -1e6f);
  }
  __syncthreads();

  /* ---- phase 2: masked softmax, 4 waves per row ---- */
  {
    const int wid = t >> 6, lane = t & 63;
    const int row = wid >> 2, seg = wid & 3;
    const int kb = seg * 256 + lane;
    float v0 = st[(kb      ) * 4 + row];
    float v1 = st[(kb +  64) * 4 + row];
    float v2 = st[(kb + 128) * 4 + row];
    float v3 = st[(kb + 192) * 4 + row];
    float m = fmaxf(fmaxf(v0, v1), fmaxf(v2, v3));
    for (int o = 32; o; o >>= 1) m = fmaxf(m, __shfl_xor(m, o));
    if (lane == 0) pm[wid] = m;
    __syncthreads();
    m = fmaxf(fmaxf(pm[row*4+0], pm[row*4+1]), fmaxf(pm[row*4+2], pm[row*4+3]));
    float e0 = __builtin_amdgcn_exp2f((v0 - m) * L2E);
    float e1 = __builtin_amdgcn_exp2f((v1 - m) * L2E);
    float e2 = __builtin_amdgcn_exp2f((v2 - m) * L2E);
    float e3 = __builtin_amdgcn_exp2f((v3 - m) * L2E);
    float sm = e0 + e1 + e2 + e3;
    for (int o = 32; o; o >>= 1) sm += __shfl_xor(sm, o);
    if (lane == 0) psm[wid] = sm;
    __syncthreads();
    const float S = psm[row*4+0] + psm[row*4+1] + psm[row*4+2] + psm[row*4+3];
    const float rr = 1.0f / S;
    st[(kb      ) * 4 + row] = e0 * rr;
    st[(kb +  64) * 4 + row] = e1 * rr;
    st[(kb + 128) * 4 + row] = e2 * rr;
    st[(kb + 192) * 4 + row] = e3 * rr;
  }
  __syncthreads();

  /* ---- phase 3: PV, split-k quarters; values[b] read once per block ---- */
  {
    const int kq = t >> 8, c2 = (t & 255) * 2;
    const float* vb = vals + (size_t)b * NK * ND + c2;
    float ox0=0.f, oy0=0.f, ox1=0.f, oy1=0.f;
    float ox2=0.f, oy2=0.f, ox3=0.f, oy3=0.f;
    const int k0 = kq * 256;
    #pragma unroll 8
    for (int k = k0; k < k0 + 256; ++k) {
      float2 v2 = *(const float2*)(vb + (size_t)k * ND);
      float4 a  = *(const float4*)&st[k * 4];
      ox0 += a.x * v2.x; oy0 += a.x * v2.y;
      ox1 += a.y * v2.x; oy1 += a.y * v2.y;
      ox2 += a.z * v2.x; oy2 += a.z * v2.y;
      ox3 += a.w * v2.x; oy3 += a.w * v2.y;
    }
    float* pp = &part[(size_t)kq * QROWS * ND + c2];
    *(float2*)(pp         ) = make_float2(ox0, oy0);
    *(float2*)(pp +     ND) = make_float2(ox1, oy1);
    *(float2*)(pp + 2 * ND) = make_float2(ox2, oy2);
    *(float2*)(pp + 3 * ND) = make_float2(ox3, oy3);
  }
  __syncthreads();
  {
    const int r = t >> 8, c2 = (t & 255) * 2;
    const float* pp = &part[(size_t)r * ND + c2];
    float2 s = make_float2(0.f, 0.f);
    #pragma unroll
    for (int kq = 0; kq < 4; ++kq) {
      float2 p = *(const float2*)(pp + (size_t)kq * QROWS * ND);
      s.x += p.x; s.y += p.y;
    }
    *(float2*)(out + ((size_t)b * NQ + q0 + r) * ND + c2) = s;
  }
}

extern "C" void kernel_launch(void* const* d_in, const int* in_sizes, int n_in,
                              void* d_out, int out_size, void* d_ws, size_t ws_size,
                              hipStream_t stream) {
  const float* queries = (const float*)d_in[0];
  const float* keys    = (const float*)d_in[1];
  const float* values  = (const float*)d_in[2];
  const int*   vlens   = (const int*)d_in[3];
  const float* Wq      = (const float*)d_in[4];
  const float* Wk      = (const float*)d_in[5];
  const float* wv      = (const float*)d_in[6];
  float* out = (float*)d_out;               /* F32 OUTPUT */

  float* qp  = (float*)d_ws;                /* [B][Q][H]   1 MB, pre-scaled */
  float* kp  = qp  + (size_t)NB * NQ * NH;  /* [B][H][K]   4 MB, pre-scaled */
  float* wtq = kp  + (size_t)NB * NH * NK;  /* [D/4][H]x4  512 KB */
  float* wtk = wtq + (size_t)(ND / 4) * NH * 4; /*         512 KB */

  ff_wt  <<<dim3(128, 2), 256, 0, stream>>>(Wq, Wk, wtq, wtk);
  ff_proj<<<dim3(NB * NQ / PRJ_R + NB * NK / PRJ_R), 256, 0, stream>>>(
      queries, keys, wtq, wtk, qp, kp);
  ff_attn<<<dim3(NQ / QROWS, NB), 1024, 0, stream>>>(qp, kp, values, vlens, wv, out);
}